// Round 15
// baseline (155.408 us; speedup 1.0000x reference)
//
#include <hip/hip_runtime.h>
#include <hip/hip_bf16.h>
#include <cstdint>
#include <cstddef>

#define BB 16
#define CC 256
#define LL 4096
#define KNUM 1024
#define NFRM (BB * LL)      // 65536 frames
#define QCAP 1536           // block-local candidate queue capacity
#define BAND 0.012f

static const size_t NOUT = (size_t)BB * CC * LL;   // 16777216 floats

typedef __attribute__((ext_vector_type(8))) short short8v;
typedef __attribute__((ext_vector_type(4))) float f32x4;
typedef __attribute__((ext_vector_type(8))) __bf16 bf16x8;

__device__ __forceinline__ f32x4 mfma16(short8v a, short8v b, f32x4 c) {
    return __builtin_amdgcn_mfma_f32_16x16x32_bf16(
        __builtin_bit_cast(bf16x8, a), __builtin_bit_cast(bf16x8, b), c, 0, 0, 0);
}

__device__ __forceinline__ short bf16bits(float v) {
    __hip_bfloat16 h = __float2bfloat16(v);
    return *reinterpret_cast<short*>(&h);
}

// pack (sim, k) so that u64-max == (greater sim, else lower k)
__device__ __forceinline__ unsigned long long packkey(float s, int k) {
    unsigned int sb = __float_as_uint(s);
    sb = (sb & 0x80000000u) ? ~sb : (sb | 0x80000000u);
    return ((unsigned long long)sb << 32) | (unsigned long long)(1023 - k);
}

// ------------------------------------------------------- K1: codebook norms
// BYTE-IDENTICAL math to rounds 3-14.
__global__ void k_cbnorm(const float* __restrict__ cb, float* __restrict__ en,
                         float* __restrict__ enorm2, short* __restrict__ enh) {
    __shared__ double wsum[4];
    const int k = blockIdx.x, c = threadIdx.x;
    float v = cb[(size_t)k * CC + c];
    double d = (double)v * (double)v;
#pragma unroll
    for (int m = 32; m >= 1; m >>= 1) d += __shfl_down(d, m);
    const int wv = c >> 6, ln = c & 63;
    if (ln == 0) wsum[wv] = d;
    __syncthreads();
    const double tot = wsum[0] + wsum[1] + wsum[2] + wsum[3];
    const float s32 = (float)tot;
    const float rn = 1.0f / sqrtf(s32 + 1e-12f);
    const float e = v * rn;                 // one fp32 rounding, like ref
    en[(size_t)k * CC + c] = e;
    enh[(size_t)k * CC + c] = bf16bits(e);
    double e2 = (double)e * (double)e;
#pragma unroll
    for (int m = 32; m >= 1; m >>= 1) e2 += __shfl_down(e2, m);
    __syncthreads();
    if (ln == 0) wsum[wv] = e2;
    __syncthreads();
    if (c == 0) enorm2[k] = (float)(wsum[0] + wsum[1] + wsum[2] + wsum[3]);
}

// ---------------- K2: MEGA — norms + A-stage + GEMM/queue + resolve + gather
#define BLOAD(dst, kcv, csv)                                                   \
    _Pragma("unroll")                                                          \
    for (int kt = 0; kt < 4; ++kt)                                             \
        dst[kt] = *(const short8v*)&enh[(size_t)((kcv) * 256 + w * 64 +        \
                                                 kt * 16 + lr) * 256 +         \
                                        (csv) * 32 + lg * 8];

#define ALOAD(dst, csv)                                                        \
    _Pragma("unroll")                                                          \
    for (int ft = 0; ft < 4; ++ft) {                                           \
        int fr = ft * 16 + lr;                                                 \
        dst[ft] = *(const short8v*)&A[(fr * 256 + (csv) * 32 + lg * 8) ^       \
                                      ((lr & 7) << 3)];                        \
    }

__global__ __launch_bounds__(256, 2) void k_mega(
    const float* __restrict__ x, const float* __restrict__ en,
    const float* __restrict__ enorm2, const short* __restrict__ enh,
    float* __restrict__ out, float* __restrict__ loss) {
    __shared__ char U[64 * 257 * 4];       // union: A bf16[64x256] / xn f32[64x257] / ens
    __shared__ double red[4][64];
    __shared__ float rns_l[64];
    __shared__ float nxn_l[64];
    __shared__ unsigned short qd[QCAP];
    __shared__ unsigned long long pk_l[64];
    __shared__ float wmax[256];            // [w][ft][lg][r]
    __shared__ int qn;

    short* A = (short*)U;
    float* xn = (float*)U;

    const int tid = threadIdx.x;
    const int w = tid >> 6;
    const int l = tid & 63;
    const int lr = l & 15, lg = l >> 4;
    const int b = blockIdx.x >> 6;
    const int l0 = (blockIdx.x & 63) << 6;
    const float* xp = x + (size_t)b * CC * LL + l0 + l;

    // ---- phase 1: fp64 norms (EXACT xt2 pass-1 semantics)
    {
        double s0 = 0.0, s1 = 0.0, s2 = 0.0, s3 = 0.0;
#pragma unroll 4
        for (int i = 0; i < 64; i += 4) {
            int c = w * 64 + i;
            float v0 = xp[(size_t)(c + 0) * LL];
            float v1 = xp[(size_t)(c + 1) * LL];
            float v2 = xp[(size_t)(c + 2) * LL];
            float v3 = xp[(size_t)(c + 3) * LL];
            s0 += (double)v0 * v0; s1 += (double)v1 * v1;
            s2 += (double)v2 * v2; s3 += (double)v3 * v3;
        }
        red[w][l] = (s0 + s1) + (s2 + s3);
    }
    __syncthreads();
    if (tid < 64) {
        double tot = (red[0][tid] + red[1][tid]) + (red[2][tid] + red[3][tid]);
        const float s32 = (float)tot;
        const float rn = 1.0f / sqrtf(s32 + 1e-12f);
        rns_l[tid] = rn;
        nxn_l[tid] = s32 * rn * rn;
        pk_l[tid] = 0ull;
    }
    if (tid == 0) qn = 0;
    __syncthreads();

    // ---- phase 2: bf16 convert + transpose A into LDS (swizzled) — L2-hot re-read
    {
        const float rn = rns_l[l];
#pragma unroll
        for (int i8 = 0; i8 < 8; ++i8) {
            int cb = w * 64 + i8 * 8;
            short8v o;
#pragma unroll
            for (int j = 0; j < 8; ++j)
                o[j] = bf16bits(xp[(size_t)(cb + j) * LL] * rn);
            *(short8v*)&A[(l * 256 + cb) ^ ((l & 7) << 3)] = o;
        }
    }
    __syncthreads();

    // ---- phase 3: GEMM + candidate queue (r9 structure + af ping-pong pipeline)
    float runmax[4][4];
#pragma unroll
    for (int i = 0; i < 4; ++i)
#pragma unroll
        for (int r = 0; r < 4; ++r) runmax[i][r] = -3e38f;

    short8v breg[2][4];
    short8v afbuf[2][4];
    BLOAD(breg[0], 0, 0);
    ALOAD(afbuf[0], 0);

    for (int kc = 0; kc < 4; ++kc) {
        f32x4 acc[4][4];
#pragma unroll
        for (int ft = 0; ft < 4; ++ft)
#pragma unroll
            for (int kt = 0; kt < 4; ++kt) acc[ft][kt] = (f32x4){0.f, 0.f, 0.f, 0.f};

#pragma unroll
        for (int cs = 0; cs < 8; ++cs) {
            const int cur = cs & 1, nxt = cur ^ 1;
            if (cs < 7) {
                BLOAD(breg[nxt], kc, cs + 1);
            } else if (kc < 3) {
                BLOAD(breg[nxt], kc + 1, 0);
            }
            // issue NEXT step's A-fragment ds_reads before this step's MFMAs
            // ((cs+1)&7 == 0 reloads cs=0 fragments — identical across kc)
            ALOAD(afbuf[nxt], (cs + 1) & 7);
#pragma unroll
            for (int kt = 0; kt < 4; ++kt)
#pragma unroll
                for (int ft = 0; ft < 4; ++ft)
                    acc[ft][kt] = mfma16(afbuf[cur][ft], breg[cur][kt], acc[ft][kt]);
        }

        // ---- epilogue: cross-wave global prefix max + banded LDS-queue appends
        float mloc[4][4];
#pragma unroll
        for (int ft = 0; ft < 4; ++ft)
#pragma unroll
            for (int r = 0; r < 4; ++r) {
                float m = fmaxf(fmaxf(acc[ft][0][r], acc[ft][1][r]),
                                fmaxf(acc[ft][2][r], acc[ft][3][r]));
#pragma unroll
                for (int mm = 1; mm < 16; mm <<= 1) m = fmaxf(m, __shfl_xor(m, mm));
                mloc[ft][r] = m;
            }
        if (lr == 0) {
#pragma unroll
            for (int ft = 0; ft < 4; ++ft)
#pragma unroll
                for (int r = 0; r < 4; ++r)
                    wmax[((w * 4 + ft) * 4 + lg) * 4 + r] = mloc[ft][r];
        }
        __syncthreads();
#pragma unroll
        for (int ft = 0; ft < 4; ++ft) {
#pragma unroll
            for (int r = 0; r < 4; ++r) {
                float gm = fmaxf(
                    fmaxf(wmax[((0 * 4 + ft) * 4 + lg) * 4 + r],
                          wmax[((1 * 4 + ft) * 4 + lg) * 4 + r]),
                    fmaxf(wmax[((2 * 4 + ft) * 4 + lg) * 4 + r],
                          wmax[((3 * 4 + ft) * 4 + lg) * 4 + r]));
                float rm = fmaxf(runmax[ft][r], gm);
                runmax[ft][r] = rm;
                const float thr = rm - BAND;
                const int fl = ft * 16 + lg * 4 + r;
#pragma unroll
                for (int kt = 0; kt < 4; ++kt) {
                    if (acc[ft][kt][r] >= thr) {
                        int kg = kc * 256 + w * 64 + kt * 16 + lr;
                        int slot = atomicAdd(&qn, 1);          // LDS atomic
                        if (slot < QCAP)
                            qd[slot] = (unsigned short)((fl << 10) | kg);
                    }
                }
            }
        }
        __syncthreads();   // wmax reusable next kc; last iter = fence before phase 4
    }

    const int n = qn;

    // ---- phase 4: stage fp32 xn into LDS (A is dead; union reuse), float4 loads
    {
        const float* xb = x + (size_t)b * CC * LL + l0;
        const int l4 = (tid & 15) << 2;
        const float r0 = rns_l[l4 + 0], r1 = rns_l[l4 + 1];
        const float r2 = rns_l[l4 + 2], r3 = rns_l[l4 + 3];
#pragma unroll 4
        for (int it = 0; it < 16; ++it) {
            const int c = it * 16 + (tid >> 4);
            f32x4 v = *(const f32x4*)&xb[(size_t)c * LL + l4];
            xn[(l4 + 0) * 257 + c] = v[0] * r0;
            xn[(l4 + 1) * 257 + c] = v[1] * r1;
            xn[(l4 + 2) * 257 + c] = v[2] * r2;
            xn[(l4 + 3) * 257 + c] = v[3] * r3;
        }
    }
    __syncthreads();

    // ---- phase 5: exact seq-fp32 resolve into LDS packed keys
    if (n <= QCAP) {
        for (int e = tid; e < n; e += 256) {
            const unsigned short ent = qd[e];
            const int fl = ent >> 10, k = ent & 1023;
            const f32x4* er4 = (const f32x4*)(en + (size_t)k * CC);
            const float* xr = &xn[fl * 257];
            float s = 0.f;
#pragma unroll 8
            for (int c4 = 0; c4 < 64; ++c4) {      // ascending c, sequential FMA
                f32x4 ev = er4[c4];
                s = fmaf(xr[c4 * 4 + 0], ev[0], s);
                s = fmaf(xr[c4 * 4 + 1], ev[1], s);
                s = fmaf(xr[c4 * 4 + 2], ev[2], s);
                s = fmaf(xr[c4 * 4 + 3], ev[3], s);
            }
            atomicMax(&pk_l[fl], packkey(s, k));
        }
    } else {
        // overflow (~never): exact full scan, 4 threads per frame x 256 k each
        const int fl = tid >> 2, q = tid & 3;
        const float* xr = &xn[fl * 257];
        unsigned long long best = 0ull;
        for (int k = q * 256; k < q * 256 + 256; ++k) {
            const f32x4* er4 = (const f32x4*)(en + (size_t)k * CC);
            float s = 0.f;
#pragma unroll 8
            for (int c4 = 0; c4 < 64; ++c4) {
                f32x4 ev = er4[c4];
                s = fmaf(xr[c4 * 4 + 0], ev[0], s);
                s = fmaf(xr[c4 * 4 + 1], ev[1], s);
                s = fmaf(xr[c4 * 4 + 2], ev[2], s);
                s = fmaf(xr[c4 * 4 + 3], ev[3], s);
            }
            unsigned long long key = packkey(s, k);
            if (key > best) best = key;
        }
        atomicMax(&pk_l[fl], best);
    }
    __syncthreads();

    // ---- phase 6: gather winner rows (reuse union as ens), write out, loss
    float* ens = xn;
    for (int j = 0; j < 64; ++j) {
        int kwj = 1023 - (int)(pk_l[j] & 1023ull);
        ens[j * 257 + tid] = en[(size_t)kwj * CC + tid];
    }
    __syncthreads();
    {
        float* ob = out + (size_t)b * CC * LL + l0;
        const int fl = tid & 63, cq = tid >> 6;
#pragma unroll 4
        for (int i = 0; i < 64; ++i) {
            int c = cq * 64 + i;
            ob[(size_t)c * LL + fl] = ens[fl * 257 + c];
        }
    }
    if (tid < 64) {
        unsigned long long v = pk_l[tid];
        int kw = 1023 - (int)(v & 1023ull);
        unsigned int hi = (unsigned int)(v >> 32);
        unsigned int sb = (hi & 0x80000000u) ? (hi ^ 0x80000000u) : ~hi;
        float sim = __uint_as_float(sb);
        float part = nxn_l[tid] + enorm2[kw] - 2.0f * sim;
#pragma unroll
        for (int m = 32; m >= 1; m >>= 1) part += __shfl_xor(part, m);
        if (tid == 0) atomicAdd(loss, part * (1.25f / 16777216.f));
    }
}

// ------------------------------------------------------------------- launch
extern "C" void kernel_launch(void* const* d_in, const int* in_sizes, int n_in,
                              void* d_out, int out_size, void* d_ws, size_t ws_size,
                              hipStream_t stream) {
    const float* x = (const float*)d_in[0];
    const float* cb = (const float*)d_in[1];
    float* out = (float*)d_out;
    char* ws = (char*)d_ws;

    // ws scratch (~1.52 MB total)
    float* en     = (float*)(ws);                    // 1 MB
    float* enorm2 = (float*)(ws + 0x100000);         // 4 KB
    short* enh    = (short*)(ws + 0x101000);         // 512 KB

    hipMemsetAsync(out + NOUT, 0, sizeof(float), stream);

    k_cbnorm<<<KNUM, 256, 0, stream>>>(cb, en, enorm2, enh);
    k_mega<<<BB * (LL / 64), 256, 0, stream>>>(x, en, enorm2, enh, out, out + NOUT);
}

// Round 16
// 141.033 us; speedup vs baseline: 1.1019x; 1.1019x over previous
//
#include <hip/hip_runtime.h>
#include <hip/hip_bf16.h>
#include <cstdint>
#include <cstddef>

#define BB 16
#define CC 256
#define LL 4096
#define KNUM 1024
#define NFRM (BB * LL)      // 65536 frames
#define QCAP 1536           // block-local candidate queue capacity
#define BAND 0.012f

static const size_t NOUT = (size_t)BB * CC * LL;   // 16777216 floats

typedef __attribute__((ext_vector_type(8))) short short8v;
typedef __attribute__((ext_vector_type(4))) float f32x4;
typedef __attribute__((ext_vector_type(8))) __bf16 bf16x8;

__device__ __forceinline__ f32x4 mfma16(short8v a, short8v b, f32x4 c) {
    return __builtin_amdgcn_mfma_f32_16x16x32_bf16(
        __builtin_bit_cast(bf16x8, a), __builtin_bit_cast(bf16x8, b), c, 0, 0, 0);
}

__device__ __forceinline__ short bf16bits(float v) {
    __hip_bfloat16 h = __float2bfloat16(v);
    return *reinterpret_cast<short*>(&h);
}

// pack (sim, k) so that u64-max == (greater sim, else lower k)
__device__ __forceinline__ unsigned long long packkey(float s, int k) {
    unsigned int sb = __float_as_uint(s);
    sb = (sb & 0x80000000u) ? ~sb : (sb | 0x80000000u);
    return ((unsigned long long)sb << 32) | (unsigned long long)(1023 - k);
}

// ------------------------------------------------------- K1: codebook norms
// BYTE-IDENTICAL math to rounds 3-15. enh now written in (kc,cs)-TILED layout:
// tile t = (k>>8)*8 + (c>>5) holds 256k x 32c contiguous (16KB) so each GEMM
// step's B-slice is one dense, sequential block.
__global__ void k_cbnorm(const float* __restrict__ cb, float* __restrict__ en,
                         float* __restrict__ enorm2, short* __restrict__ enh) {
    __shared__ double wsum[4];
    const int k = blockIdx.x, c = threadIdx.x;
    float v = cb[(size_t)k * CC + c];
    double d = (double)v * (double)v;
#pragma unroll
    for (int m = 32; m >= 1; m >>= 1) d += __shfl_down(d, m);
    const int wv = c >> 6, ln = c & 63;
    if (ln == 0) wsum[wv] = d;
    __syncthreads();
    const double tot = wsum[0] + wsum[1] + wsum[2] + wsum[3];
    const float s32 = (float)tot;
    const float rn = 1.0f / sqrtf(s32 + 1e-12f);
    const float e = v * rn;                 // one fp32 rounding, like ref
    en[(size_t)k * CC + c] = e;
    enh[((size_t)((k >> 8) * 8 + (c >> 5)) << 13) + ((k & 255) << 5) + (c & 31)] =
        bf16bits(e);
    double e2 = (double)e * (double)e;
#pragma unroll
    for (int m = 32; m >= 1; m >>= 1) e2 += __shfl_down(e2, m);
    __syncthreads();
    if (ln == 0) wsum[wv] = e2;
    __syncthreads();
    if (c == 0) enorm2[k] = (float)(wsum[0] + wsum[1] + wsum[2] + wsum[3]);
}

// ---------------- K2: MEGA — norms + A-stage + GEMM/queue + resolve + gather
// BLOAD from tiled enh: per kt one fully-contiguous 1KB wave fetch.
#define BLOAD(dst, kcv, csv)                                                   \
    {                                                                          \
        const short* bt = enh + ((size_t)((kcv) * 8 + (csv)) << 13);           \
        _Pragma("unroll")                                                      \
        for (int kt = 0; kt < 4; ++kt)                                         \
            dst[kt] = *(const short8v*)&bt[(w * 64 + kt * 16 + lr) * 32 +      \
                                           lg * 8];                            \
    }

__global__ __launch_bounds__(256, 2) void k_mega(
    const float* __restrict__ x, const float* __restrict__ en,
    const float* __restrict__ enorm2, const short* __restrict__ enh,
    float* __restrict__ out, float* __restrict__ loss) {
    __shared__ char U[64 * 257 * 4];       // union: A bf16[64x256] / xn f32[64x257] / ens
    __shared__ double red[4][64];
    __shared__ float rns_l[64];
    __shared__ float nxn_l[64];
    __shared__ unsigned short qd[QCAP];
    __shared__ unsigned long long pk_l[64];
    __shared__ float wmax[256];            // [w][ft][lg][r]
    __shared__ int qn;

    short* A = (short*)U;
    float* xn = (float*)U;

    const int tid = threadIdx.x;
    const int w = tid >> 6;
    const int l = tid & 63;
    const int lr = l & 15, lg = l >> 4;
    const int b = blockIdx.x >> 6;
    const int l0 = (blockIdx.x & 63) << 6;
    const float* xp = x + (size_t)b * CC * LL + l0 + l;

    // ---- phase 1: fp64 norms (EXACT xt2 pass-1 semantics)
    {
        double s0 = 0.0, s1 = 0.0, s2 = 0.0, s3 = 0.0;
#pragma unroll 4
        for (int i = 0; i < 64; i += 4) {
            int c = w * 64 + i;
            float v0 = xp[(size_t)(c + 0) * LL];
            float v1 = xp[(size_t)(c + 1) * LL];
            float v2 = xp[(size_t)(c + 2) * LL];
            float v3 = xp[(size_t)(c + 3) * LL];
            s0 += (double)v0 * v0; s1 += (double)v1 * v1;
            s2 += (double)v2 * v2; s3 += (double)v3 * v3;
        }
        red[w][l] = (s0 + s1) + (s2 + s3);
    }
    __syncthreads();
    if (tid < 64) {
        double tot = (red[0][tid] + red[1][tid]) + (red[2][tid] + red[3][tid]);
        const float s32 = (float)tot;
        const float rn = 1.0f / sqrtf(s32 + 1e-12f);
        rns_l[tid] = rn;
        nxn_l[tid] = s32 * rn * rn;
        pk_l[tid] = 0ull;
    }
    if (tid == 0) qn = 0;
    __syncthreads();

    // ---- phase 2: bf16 convert + transpose A into LDS (swizzled) — L2-hot re-read
    {
        const float rn = rns_l[l];
#pragma unroll
        for (int i8 = 0; i8 < 8; ++i8) {
            int cb = w * 64 + i8 * 8;
            short8v o;
#pragma unroll
            for (int j = 0; j < 8; ++j)
                o[j] = bf16bits(xp[(size_t)(cb + j) * LL] * rn);
            *(short8v*)&A[(l * 256 + cb) ^ ((l & 7) << 3)] = o;
        }
    }
    __syncthreads();

    // ---- phase 3: GEMM + candidate queue (r14/r9 structure, tiled-B loads)
    float runmax[4][4];
#pragma unroll
    for (int i = 0; i < 4; ++i)
#pragma unroll
        for (int r = 0; r < 4; ++r) runmax[i][r] = -3e38f;

    short8v breg[2][4];
    BLOAD(breg[0], 0, 0);

    for (int kc = 0; kc < 4; ++kc) {
        f32x4 acc[4][4];
#pragma unroll
        for (int ft = 0; ft < 4; ++ft)
#pragma unroll
            for (int kt = 0; kt < 4; ++kt) acc[ft][kt] = (f32x4){0.f, 0.f, 0.f, 0.f};

#pragma unroll
        for (int cs = 0; cs < 8; ++cs) {
            const int cur = cs & 1, nxt = cur ^ 1;
            if (cs < 7) {
                BLOAD(breg[nxt], kc, cs + 1);
            } else if (kc < 3) {
                BLOAD(breg[nxt], kc + 1, 0);
            }
            short8v af[4];
#pragma unroll
            for (int ft = 0; ft < 4; ++ft) {
                int fr = ft * 16 + lr;
                af[ft] = *(const short8v*)&A[(fr * 256 + cs * 32 + lg * 8) ^ ((lr & 7) << 3)];
            }
#pragma unroll
            for (int kt = 0; kt < 4; ++kt)
#pragma unroll
                for (int ft = 0; ft < 4; ++ft)
                    acc[ft][kt] = mfma16(af[ft], breg[cur][kt], acc[ft][kt]);
        }

        // ---- epilogue: cross-wave global prefix max + banded LDS-queue appends
        float mloc[4][4];
#pragma unroll
        for (int ft = 0; ft < 4; ++ft)
#pragma unroll
            for (int r = 0; r < 4; ++r) {
                float m = fmaxf(fmaxf(acc[ft][0][r], acc[ft][1][r]),
                                fmaxf(acc[ft][2][r], acc[ft][3][r]));
#pragma unroll
                for (int mm = 1; mm < 16; mm <<= 1) m = fmaxf(m, __shfl_xor(m, mm));
                mloc[ft][r] = m;
            }
        if (lr == 0) {
#pragma unroll
            for (int ft = 0; ft < 4; ++ft)
#pragma unroll
                for (int r = 0; r < 4; ++r)
                    wmax[((w * 4 + ft) * 4 + lg) * 4 + r] = mloc[ft][r];
        }
        __syncthreads();
#pragma unroll
        for (int ft = 0; ft < 4; ++ft) {
#pragma unroll
            for (int r = 0; r < 4; ++r) {
                float gm = fmaxf(
                    fmaxf(wmax[((0 * 4 + ft) * 4 + lg) * 4 + r],
                          wmax[((1 * 4 + ft) * 4 + lg) * 4 + r]),
                    fmaxf(wmax[((2 * 4 + ft) * 4 + lg) * 4 + r],
                          wmax[((3 * 4 + ft) * 4 + lg) * 4 + r]));
                float rm = fmaxf(runmax[ft][r], gm);
                runmax[ft][r] = rm;
                const float thr = rm - BAND;
                const int fl = ft * 16 + lg * 4 + r;
#pragma unroll
                for (int kt = 0; kt < 4; ++kt) {
                    if (acc[ft][kt][r] >= thr) {
                        int kg = kc * 256 + w * 64 + kt * 16 + lr;
                        int slot = atomicAdd(&qn, 1);          // LDS atomic
                        if (slot < QCAP)
                            qd[slot] = (unsigned short)((fl << 10) | kg);
                    }
                }
            }
        }
        __syncthreads();   // wmax reusable next kc; last iter = fence before phase 4
    }

    const int n = qn;

    // ---- phase 4: stage fp32 xn into LDS (A is dead; union reuse), float4 loads
    {
        const float* xb = x + (size_t)b * CC * LL + l0;
        const int l4 = (tid & 15) << 2;
        const float r0 = rns_l[l4 + 0], r1 = rns_l[l4 + 1];
        const float r2 = rns_l[l4 + 2], r3 = rns_l[l4 + 3];
#pragma unroll 4
        for (int it = 0; it < 16; ++it) {
            const int c = it * 16 + (tid >> 4);
            f32x4 v = *(const f32x4*)&xb[(size_t)c * LL + l4];
            xn[(l4 + 0) * 257 + c] = v[0] * r0;
            xn[(l4 + 1) * 257 + c] = v[1] * r1;
            xn[(l4 + 2) * 257 + c] = v[2] * r2;
            xn[(l4 + 3) * 257 + c] = v[3] * r3;
        }
    }
    __syncthreads();

    // ---- phase 5: exact seq-fp32 resolve into LDS packed keys
    if (n <= QCAP) {
        for (int e = tid; e < n; e += 256) {
            const unsigned short ent = qd[e];
            const int fl = ent >> 10, k = ent & 1023;
            const f32x4* er4 = (const f32x4*)(en + (size_t)k * CC);
            const float* xr = &xn[fl * 257];
            float s = 0.f;
#pragma unroll 8
            for (int c4 = 0; c4 < 64; ++c4) {      // ascending c, sequential FMA
                f32x4 ev = er4[c4];
                s = fmaf(xr[c4 * 4 + 0], ev[0], s);
                s = fmaf(xr[c4 * 4 + 1], ev[1], s);
                s = fmaf(xr[c4 * 4 + 2], ev[2], s);
                s = fmaf(xr[c4 * 4 + 3], ev[3], s);
            }
            atomicMax(&pk_l[fl], packkey(s, k));
        }
    } else {
        // overflow (~never): exact full scan, 4 threads per frame x 256 k each
        const int fl = tid >> 2, q = tid & 3;
        const float* xr = &xn[fl * 257];
        unsigned long long best = 0ull;
        for (int k = q * 256; k < q * 256 + 256; ++k) {
            const f32x4* er4 = (const f32x4*)(en + (size_t)k * CC);
            float s = 0.f;
#pragma unroll 8
            for (int c4 = 0; c4 < 64; ++c4) {
                f32x4 ev = er4[c4];
                s = fmaf(xr[c4 * 4 + 0], ev[0], s);
                s = fmaf(xr[c4 * 4 + 1], ev[1], s);
                s = fmaf(xr[c4 * 4 + 2], ev[2], s);
                s = fmaf(xr[c4 * 4 + 3], ev[3], s);
            }
            unsigned long long key = packkey(s, k);
            if (key > best) best = key;
        }
        atomicMax(&pk_l[fl], best);
    }
    __syncthreads();

    // ---- phase 6: gather winner rows (reuse union as ens), write out, loss
    float* ens = xn;
    for (int j = 0; j < 64; ++j) {
        int kwj = 1023 - (int)(pk_l[j] & 1023ull);
        ens[j * 257 + tid] = en[(size_t)kwj * CC + tid];
    }
    __syncthreads();
    {
        float* ob = out + (size_t)b * CC * LL + l0;
        const int fl = tid & 63, cq = tid >> 6;
#pragma unroll 4
        for (int i = 0; i < 64; ++i) {
            int c = cq * 64 + i;
            ob[(size_t)c * LL + fl] = ens[fl * 257 + c];
        }
    }
    if (tid < 64) {
        unsigned long long v = pk_l[tid];
        int kw = 1023 - (int)(v & 1023ull);
        unsigned int hi = (unsigned int)(v >> 32);
        unsigned int sb = (hi & 0x80000000u) ? (hi ^ 0x80000000u) : ~hi;
        float sim = __uint_as_float(sb);
        float part = nxn_l[tid] + enorm2[kw] - 2.0f * sim;
#pragma unroll
        for (int m = 32; m >= 1; m >>= 1) part += __shfl_xor(part, m);
        if (tid == 0) atomicAdd(loss, part * (1.25f / 16777216.f));
    }
}

// ------------------------------------------------------------------- launch
extern "C" void kernel_launch(void* const* d_in, const int* in_sizes, int n_in,
                              void* d_out, int out_size, void* d_ws, size_t ws_size,
                              hipStream_t stream) {
    const float* x = (const float*)d_in[0];
    const float* cb = (const float*)d_in[1];
    float* out = (float*)d_out;
    char* ws = (char*)d_ws;

    // ws scratch (~1.52 MB total)
    float* en     = (float*)(ws);                    // 1 MB
    float* enorm2 = (float*)(ws + 0x100000);         // 4 KB
    short* enh    = (short*)(ws + 0x101000);         // 512 KB (tiled layout)

    hipMemsetAsync(out + NOUT, 0, sizeof(float), stream);

    k_cbnorm<<<KNUM, 256, 0, stream>>>(cb, en, enorm2, enh);
    k_mega<<<BB * (LL / 64), 256, 0, stream>>>(x, en, enorm2, enh, out, out + NOUT);
}

// Round 17
// 137.542 us; speedup vs baseline: 1.1299x; 1.0254x over previous
//
#include <hip/hip_runtime.h>
#include <hip/hip_bf16.h>
#include <cstdint>
#include <cstddef>

#define BB 16
#define CC 256
#define LL 4096
#define KNUM 1024
#define NFRM (BB * LL)      // 65536 frames
#define QCAP 1536           // block-local candidate queue capacity
#define BAND 0.012f

static const size_t NOUT = (size_t)BB * CC * LL;   // 16777216 floats

typedef __attribute__((ext_vector_type(8))) short short8v;
typedef __attribute__((ext_vector_type(4))) float f32x4;
typedef __attribute__((ext_vector_type(8))) __bf16 bf16x8;

__device__ __forceinline__ f32x4 mfma16(short8v a, short8v b, f32x4 c) {
    return __builtin_amdgcn_mfma_f32_16x16x32_bf16(
        __builtin_bit_cast(bf16x8, a), __builtin_bit_cast(bf16x8, b), c, 0, 0, 0);
}

__device__ __forceinline__ short bf16bits(float v) {
    __hip_bfloat16 h = __float2bfloat16(v);
    return *reinterpret_cast<short*>(&h);
}

// pack (sim, k) so that u64-max == (greater sim, else lower k)
__device__ __forceinline__ unsigned long long packkey(float s, int k) {
    unsigned int sb = __float_as_uint(s);
    sb = (sb & 0x80000000u) ? ~sb : (sb | 0x80000000u);
    return ((unsigned long long)sb << 32) | (unsigned long long)(1023 - k);
}

// ------------------------------------------------------- K1: codebook norms
// BYTE-IDENTICAL math to rounds 3-16. enh in (kc,cs)-TILED layout:
// tile t = (k>>8)*8 + (c>>5) holds 256k x 32c contiguous (16KB).
__global__ void k_cbnorm(const float* __restrict__ cb, float* __restrict__ en,
                         float* __restrict__ enorm2, short* __restrict__ enh) {
    __shared__ double wsum[4];
    const int k = blockIdx.x, c = threadIdx.x;
    float v = cb[(size_t)k * CC + c];
    double d = (double)v * (double)v;
#pragma unroll
    for (int m = 32; m >= 1; m >>= 1) d += __shfl_down(d, m);
    const int wv = c >> 6, ln = c & 63;
    if (ln == 0) wsum[wv] = d;
    __syncthreads();
    const double tot = wsum[0] + wsum[1] + wsum[2] + wsum[3];
    const float s32 = (float)tot;
    const float rn = 1.0f / sqrtf(s32 + 1e-12f);
    const float e = v * rn;                 // one fp32 rounding, like ref
    en[(size_t)k * CC + c] = e;
    enh[((size_t)((k >> 8) * 8 + (c >> 5)) << 13) + ((k & 255) << 5) + (c & 31)] =
        bf16bits(e);
    double e2 = (double)e * (double)e;
#pragma unroll
    for (int m = 32; m >= 1; m >>= 1) e2 += __shfl_down(e2, m);
    __syncthreads();
    if (ln == 0) wsum[wv] = e2;
    __syncthreads();
    if (c == 0) enorm2[k] = (float)(wsum[0] + wsum[1] + wsum[2] + wsum[3]);
}

// ---------------- K2: MEGA — norms + A-stage + GEMM/queue + resolve + gather
// Wave tile now 64f x 128k (kt=8, kc=2): half the A ds_reads per MFMA, half
// the epilogues/barriers. Per (kc,w) all 8 kt live in one 256k tile:
// tile = kc*2 + (w>>1), in-tile k = (w&1)*128 + kt*16 + lr.
#define BLOAD8(dst, kcv, csv)                                                  \
    {                                                                          \
        const short* bt = enh +                                                \
            ((size_t)((((kcv) * 2 + (w >> 1)) * 8 + (csv)) ) << 13);           \
        _Pragma("unroll")                                                      \
        for (int kt = 0; kt < 8; ++kt)                                         \
            dst[kt] = *(const short8v*)&bt[(kb + kt * 16 + lr) * 32 + lg * 8]; \
    }

__global__ __launch_bounds__(256, 2) void k_mega(
    const float* __restrict__ x, const float* __restrict__ en,
    const float* __restrict__ enorm2, const short* __restrict__ enh,
    float* __restrict__ out, float* __restrict__ loss) {
    __shared__ char U[64 * 257 * 4];       // union: A bf16[64x256] / xn f32[64x257] / ens
    __shared__ double red[4][64];
    __shared__ float rns_l[64];
    __shared__ float nxn_l[64];
    __shared__ unsigned short qd[QCAP];
    __shared__ unsigned long long pk_l[64];
    __shared__ float wmax[256];            // [w][ft][lg][r]
    __shared__ int qn;

    short* A = (short*)U;
    float* xn = (float*)U;

    const int tid = threadIdx.x;
    const int w = tid >> 6;
    const int l = tid & 63;
    const int lr = l & 15, lg = l >> 4;
    const int kb = (w & 1) * 128;          // in-tile k base for BLOAD8
    const int b = blockIdx.x >> 6;
    const int l0 = (blockIdx.x & 63) << 6;
    const float* xp = x + (size_t)b * CC * LL + l0 + l;

    // ---- phase 1: fp64 norms (EXACT xt2 pass-1 semantics)
    {
        double s0 = 0.0, s1 = 0.0, s2 = 0.0, s3 = 0.0;
#pragma unroll 4
        for (int i = 0; i < 64; i += 4) {
            int c = w * 64 + i;
            float v0 = xp[(size_t)(c + 0) * LL];
            float v1 = xp[(size_t)(c + 1) * LL];
            float v2 = xp[(size_t)(c + 2) * LL];
            float v3 = xp[(size_t)(c + 3) * LL];
            s0 += (double)v0 * v0; s1 += (double)v1 * v1;
            s2 += (double)v2 * v2; s3 += (double)v3 * v3;
        }
        red[w][l] = (s0 + s1) + (s2 + s3);
    }
    __syncthreads();
    if (tid < 64) {
        double tot = (red[0][tid] + red[1][tid]) + (red[2][tid] + red[3][tid]);
        const float s32 = (float)tot;
        const float rn = 1.0f / sqrtf(s32 + 1e-12f);
        rns_l[tid] = rn;
        nxn_l[tid] = s32 * rn * rn;
        pk_l[tid] = 0ull;
    }
    if (tid == 0) qn = 0;
    __syncthreads();

    // ---- phase 2: bf16 convert + transpose A into LDS (swizzled) — L2-hot re-read
    {
        const float rn = rns_l[l];
#pragma unroll
        for (int i8 = 0; i8 < 8; ++i8) {
            int cb = w * 64 + i8 * 8;
            short8v o;
#pragma unroll
            for (int j = 0; j < 8; ++j)
                o[j] = bf16bits(xp[(size_t)(cb + j) * LL] * rn);
            *(short8v*)&A[(l * 256 + cb) ^ ((l & 7) << 3)] = o;
        }
    }
    __syncthreads();

    // ---- phase 3: GEMM + candidate queue (kt=8, kc=2; tiled-B; guarded appends)
    float runmax[4][4];
#pragma unroll
    for (int i = 0; i < 4; ++i)
#pragma unroll
        for (int r = 0; r < 4; ++r) runmax[i][r] = -3e38f;

    short8v breg[2][8];
    BLOAD8(breg[0], 0, 0);

#pragma unroll
    for (int kc = 0; kc < 2; ++kc) {
        f32x4 acc[4][8];
#pragma unroll
        for (int ft = 0; ft < 4; ++ft)
#pragma unroll
            for (int kt = 0; kt < 8; ++kt) acc[ft][kt] = (f32x4){0.f, 0.f, 0.f, 0.f};

#pragma unroll
        for (int cs = 0; cs < 8; ++cs) {
            const int cur = cs & 1, nxt = cur ^ 1;
            if (cs < 7) {
                BLOAD8(breg[nxt], kc, cs + 1);
            } else if (kc < 1) {
                BLOAD8(breg[nxt], kc + 1, 0);
            }
            short8v af[4];
#pragma unroll
            for (int ft = 0; ft < 4; ++ft) {
                int fr = ft * 16 + lr;
                af[ft] = *(const short8v*)&A[(fr * 256 + cs * 32 + lg * 8) ^ ((lr & 7) << 3)];
            }
#pragma unroll
            for (int kt = 0; kt < 8; ++kt)
#pragma unroll
                for (int ft = 0; ft < 4; ++ft)
                    acc[ft][kt] = mfma16(af[ft], breg[cur][kt], acc[ft][kt]);
        }

        // ---- epilogue: cross-wave global prefix max + guarded banded appends
#pragma unroll
        for (int ft = 0; ft < 4; ++ft)
#pragma unroll
            for (int r = 0; r < 4; ++r) {
                float m = acc[ft][0][r];
#pragma unroll
                for (int kt = 1; kt < 8; ++kt) m = fmaxf(m, acc[ft][kt][r]);
#pragma unroll
                for (int mm = 1; mm < 16; mm <<= 1) m = fmaxf(m, __shfl_xor(m, mm));
                if (lr == 0) wmax[((w * 4 + ft) * 4 + lg) * 4 + r] = m;
            }
        __syncthreads();
#pragma unroll
        for (int ft = 0; ft < 4; ++ft) {
#pragma unroll
            for (int r = 0; r < 4; ++r) {
                const float w0 = wmax[((0 * 4 + ft) * 4 + lg) * 4 + r];
                const float w1 = wmax[((1 * 4 + ft) * 4 + lg) * 4 + r];
                const float w2 = wmax[((2 * 4 + ft) * 4 + lg) * 4 + r];
                const float w3 = wmax[((3 * 4 + ft) * 4 + lg) * 4 + r];
                const float gm = fmaxf(fmaxf(w0, w1), fmaxf(w2, w3));
                float rm = fmaxf(runmax[ft][r], gm);
                runmax[ft][r] = rm;
                const float thr = rm - BAND;
                const float own = wmax[((w * 4 + ft) * 4 + lg) * 4 + r];
                if (__any(own >= thr)) {       // wave-uniform skip of clean groups
                    const int fl = ft * 16 + lg * 4 + r;
#pragma unroll
                    for (int kt = 0; kt < 8; ++kt) {
                        if (acc[ft][kt][r] >= thr) {
                            int kg = kc * 512 + w * 128 + kt * 16 + lr;
                            int slot = atomicAdd(&qn, 1);          // LDS atomic
                            if (slot < QCAP)
                                qd[slot] = (unsigned short)((fl << 10) | kg);
                        }
                    }
                }
            }
        }
        __syncthreads();   // wmax reusable next kc; last iter = fence before phase 4
    }

    const int n = qn;

    // ---- phase 4: stage fp32 xn into LDS (A is dead; union reuse), float4 loads
    {
        const float* xb = x + (size_t)b * CC * LL + l0;
        const int l4 = (tid & 15) << 2;
        const float r0 = rns_l[l4 + 0], r1 = rns_l[l4 + 1];
        const float r2 = rns_l[l4 + 2], r3 = rns_l[l4 + 3];
#pragma unroll 4
        for (int it = 0; it < 16; ++it) {
            const int c = it * 16 + (tid >> 4);
            f32x4 v = *(const f32x4*)&xb[(size_t)c * LL + l4];
            xn[(l4 + 0) * 257 + c] = v[0] * r0;
            xn[(l4 + 1) * 257 + c] = v[1] * r1;
            xn[(l4 + 2) * 257 + c] = v[2] * r2;
            xn[(l4 + 3) * 257 + c] = v[3] * r3;
        }
    }
    __syncthreads();

    // ---- phase 5: exact seq-fp32 resolve into LDS packed keys
    if (n <= QCAP) {
        for (int e = tid; e < n; e += 256) {
            const unsigned short ent = qd[e];
            const int fl = ent >> 10, k = ent & 1023;
            const f32x4* er4 = (const f32x4*)(en + (size_t)k * CC);
            const float* xr = &xn[fl * 257];
            float s = 0.f;
#pragma unroll 8
            for (int c4 = 0; c4 < 64; ++c4) {      // ascending c, sequential FMA
                f32x4 ev = er4[c4];
                s = fmaf(xr[c4 * 4 + 0], ev[0], s);
                s = fmaf(xr[c4 * 4 + 1], ev[1], s);
                s = fmaf(xr[c4 * 4 + 2], ev[2], s);
                s = fmaf(xr[c4 * 4 + 3], ev[3], s);
            }
            atomicMax(&pk_l[fl], packkey(s, k));
        }
    } else {
        // overflow (~never): exact full scan, 4 threads per frame x 256 k each
        const int fl = tid >> 2, q = tid & 3;
        const float* xr = &xn[fl * 257];
        unsigned long long best = 0ull;
        for (int k = q * 256; k < q * 256 + 256; ++k) {
            const f32x4* er4 = (const f32x4*)(en + (size_t)k * CC);
            float s = 0.f;
#pragma unroll 8
            for (int c4 = 0; c4 < 64; ++c4) {
                f32x4 ev = er4[c4];
                s = fmaf(xr[c4 * 4 + 0], ev[0], s);
                s = fmaf(xr[c4 * 4 + 1], ev[1], s);
                s = fmaf(xr[c4 * 4 + 2], ev[2], s);
                s = fmaf(xr[c4 * 4 + 3], ev[3], s);
            }
            unsigned long long key = packkey(s, k);
            if (key > best) best = key;
        }
        atomicMax(&pk_l[fl], best);
    }
    __syncthreads();

    // ---- phase 6: gather winner rows (reuse union as ens), write out, loss
    float* ens = xn;
    for (int j = 0; j < 64; ++j) {
        int kwj = 1023 - (int)(pk_l[j] & 1023ull);
        ens[j * 257 + tid] = en[(size_t)kwj * CC + tid];
    }
    __syncthreads();
    {
        float* ob = out + (size_t)b * CC * LL + l0;
        const int fl = tid & 63, cq = tid >> 6;
#pragma unroll 4
        for (int i = 0; i < 64; ++i) {
            int c = cq * 64 + i;
            ob[(size_t)c * LL + fl] = ens[fl * 257 + c];
        }
    }
    if (tid < 64) {
        unsigned long long v = pk_l[tid];
        int kw = 1023 - (int)(v & 1023ull);
        unsigned int hi = (unsigned int)(v >> 32);
        unsigned int sb = (hi & 0x80000000u) ? (hi ^ 0x80000000u) : ~hi;
        float sim = __uint_as_float(sb);
        float part = nxn_l[tid] + enorm2[kw] - 2.0f * sim;
#pragma unroll
        for (int m = 32; m >= 1; m >>= 1) part += __shfl_xor(part, m);
        if (tid == 0) atomicAdd(loss, part * (1.25f / 16777216.f));
    }
}

// ------------------------------------------------------------------- launch
extern "C" void kernel_launch(void* const* d_in, const int* in_sizes, int n_in,
                              void* d_out, int out_size, void* d_ws, size_t ws_size,
                              hipStream_t stream) {
    const float* x = (const float*)d_in[0];
    const float* cb = (const float*)d_in[1];
    float* out = (float*)d_out;
    char* ws = (char*)d_ws;

    // ws scratch (~1.52 MB total)
    float* en     = (float*)(ws);                    // 1 MB
    float* enorm2 = (float*)(ws + 0x100000);         // 4 KB
    short* enh    = (short*)(ws + 0x101000);         // 512 KB (tiled layout)

    hipMemsetAsync(out + NOUT, 0, sizeof(float), stream);

    k_cbnorm<<<KNUM, 256, 0, stream>>>(cb, en, enorm2, enh);
    k_mega<<<BB * (LL / 64), 256, 0, stream>>>(x, en, enorm2, enh, out, out + NOUT);
}